// Round 20
// baseline (118.136 us; speedup 1.0000x reference)
//
#include <hip/hip_runtime.h>
#include <hip/hip_bf16.h>
#include <math.h>

#define B 2
#define N 2048
#define D 1024
#define H 16
#define HD 64

typedef __attribute__((ext_vector_type(8))) short short8;
typedef __attribute__((ext_vector_type(4))) float f32x4;
typedef __attribute__((ext_vector_type(16))) float f32x16;
typedef __attribute__((ext_vector_type(4))) unsigned short ush4;
typedef __attribute__((ext_vector_type(4))) unsigned int uint4v;

__device__ __forceinline__ float bf2f(unsigned short u) {
  unsigned int x = ((unsigned int)u) << 16;
  float f;
  __builtin_memcpy(&f, &x, 4);
  return f;
}
__device__ __forceinline__ unsigned short f2bf(float f) {
  unsigned int x;
  __builtin_memcpy(&x, &f, 4);
  x = x + 0x7fffu + ((x >> 16) & 1u);
  return (unsigned short)(x >> 16);
}
__device__ __forceinline__ unsigned int pk2(float lo, float hi) {
  union { __hip_bfloat162 h; unsigned int u; } cv;
  cv.h = __float22bfloat162_rn(make_float2(lo, hi));
  return cv.u;
}
__device__ __forceinline__ short8 mk_frag(unsigned int w0, unsigned int w1,
                                          unsigned int w2, unsigned int w3) {
  union { uint4v u; short8 s; } cv;
  cv.u = (uint4v){w0, w1, w2, w3};
  return cv.s;
}

// async global->LDS, 16B per lane. LDS dest linear (base + lane*16);
// swizzle lives in the per-lane GLOBAL address (m173/m201 pattern).
__device__ __forceinline__ void gload16(const unsigned short* g, unsigned short* l) {
  __builtin_amdgcn_global_load_lds(
      (const __attribute__((address_space(1))) unsigned int*)(const void*)g,
      (__attribute__((address_space(3))) unsigned int*)(void*)l, 16, 0, 0);
}

// ---------- prep: weight conversions + rope table + x-transpose, ONE launch ----------
__global__ __launch_bounds__(256) void prep_k(const float* __restrict__ wqkv,
                                              unsigned short* __restrict__ wqkv_bf,
                                              const float* __restrict__ wout,
                                              unsigned short* __restrict__ wout_bf,
                                              float2* __restrict__ tab,
                                              const float* __restrict__ x,
                                              unsigned short* __restrict__ xt) {
  int blk = blockIdx.x;
  int tid = threadIdx.x;
  if (blk < 4096) {
    const float* src = (blk < 3072) ? wqkv : wout;
    unsigned short* dst = (blk < 3072) ? wqkv_bf : wout_bf;
    int i = (blk < 3072 ? blk : blk - 3072) * 256 + tid;
    float4 v = ((const float4*)src)[i];
    ush4 o;
    o[0] = f2bf(v.x); o[1] = f2bf(v.y); o[2] = f2bf(v.z); o[3] = f2bf(v.w);
    *(ush4*)&dst[i * 4] = o;
  } else if (blk < 4352) {
    int idx = (blk - 4096) * 256 + tid;  // 2048*32
    int t = idx >> 5, p = idx & 31;
    float inv = powf(10000.f, -(float)p / 32.f);
    float ang = (float)t * inv;
    float s, c;
    sincosf(ang, &s, &c);
    tab[idx] = make_float2(c, s);
  } else {
    __shared__ float tile[32][33];
    int tb = blk - 4352;                 // grid (64, 32, 2) flattened
    int t0 = (tb & 63) * 32, d0 = ((tb >> 6) & 31) * 32, bb = tb >> 11;
    int tx = tid & 31, ty = tid >> 5;
#pragma unroll
    for (int i = 0; i < 4; ++i) {
      int r = ty * 4 + i;
      tile[r][tx] = x[(size_t)bb * D * N + (size_t)(d0 + r) * N + t0 + tx];
    }
    __syncthreads();
#pragma unroll
    for (int i = 0; i < 4; ++i) {
      int r = ty * 4 + i;
      xt[((size_t)(bb * N) + t0 + r) * D + d0 + tx] = f2bf(tile[tx][r]);
    }
  }
}

// ---------- GEMM qkv: 128x128 tile, BK=64, 8 waves (2m x 4n), XCD swizzle ----------
// 512 threads/block: same tile, staging, and traffic as the 4-wave version,
// but 3 co-resident blocks now give 24 waves/CU (vs 12) to hide the per-K-step
// vmcnt(0)-at-barrier drain. Per-wave output 64x32 (acc[4][2]).
__global__ __launch_bounds__(512) void gemm_qkv(const unsigned short* __restrict__ A,
                                                const unsigned short* __restrict__ Bt,
                                                unsigned short* __restrict__ qkbuf,
                                                unsigned short* __restrict__ vtbuf) {
  __shared__ unsigned short Asm[128 * 64];
  __shared__ unsigned short Bsm[128 * 64];
  const int tid = threadIdx.x;
  const int lane = tid & 63, wid = tid >> 6;   // wid 0..7
  const int ln = lane & 15, lh = lane >> 4;
  const int wr = wid >> 2, wc = wid & 3;       // 2m x 4n wave grid
  const int bid = blockIdx.x;
  const int xcd = bid & 7, j = bid >> 3;
  const int m0 = (xcd * 4 + (j & 3)) * 128;
  const int n0 = (j >> 2) * 128;

  f32x4 acc[4][2];
#pragma unroll
  for (int i = 0; i < 4; ++i)
#pragma unroll
    for (int jq = 0; jq < 2; ++jq) acc[i][jq] = (f32x4){0.f, 0.f, 0.f, 0.f};

  for (int k0 = 0; k0 < 1024; k0 += 64) {
#pragma unroll
    for (int jj = 0; jj < 2; ++jj) {
      int slot = tid + jj * 512;
      int row = slot >> 3, u = slot & 7;
      int usw = (u ^ (row & 7)) * 8;
      gload16(&A[(size_t)(m0 + row) * 1024 + k0 + usw], &Asm[slot * 8]);
    }
#pragma unroll
    for (int jj = 0; jj < 2; ++jj) {
      int slot = tid + jj * 512;
      int row = slot >> 3, u = slot & 7;
      int usw = (u ^ (row & 7)) * 8;
      gload16(&Bt[(size_t)(n0 + row) * 1024 + k0 + usw], &Bsm[slot * 8]);
    }
    __syncthreads();
#pragma unroll
    for (int s = 0; s < 2; ++s) {
      short8 af[4], bfr[2];
#pragma unroll
      for (int i = 0; i < 4; ++i) {
        int row = wr * 64 + i * 16 + ln;
        int u = ((s * 4 + lh) ^ (row & 7)) * 8;
        af[i] = *(const short8*)&Asm[row * 64 + u];
      }
#pragma unroll
      for (int jq = 0; jq < 2; ++jq) {
        int row = wc * 32 + jq * 16 + ln;
        int u = ((s * 4 + lh) ^ (row & 7)) * 8;
        bfr[jq] = *(const short8*)&Bsm[row * 64 + u];
      }
#pragma unroll
      for (int i = 0; i < 4; ++i)
#pragma unroll
        for (int jq = 0; jq < 2; ++jq)
          acc[i][jq] = __builtin_amdgcn_mfma_f32_16x16x32_bf16(af[i], bfr[jq], acc[i][jq], 0, 0, 0);
    }
    __syncthreads();
  }

#pragma unroll
  for (int i = 0; i < 4; ++i) {
    int mrow = m0 + wr * 64 + i * 16 + lh * 4;
    int bb = mrow >> 11, t = mrow & 2047;
#pragma unroll
    for (int jq = 0; jq < 2; ++jq) {
      int e = n0 + wc * 32 + jq * 16 + ln;
      if (e < 2048) {
#pragma unroll
        for (int jj = 0; jj < 4; ++jj)
          qkbuf[((size_t)(bb * N + t + jj)) * 2048 + e] = f2bf(acc[i][jq][jj]);
      } else {
        ush4 v;
#pragma unroll
        for (int jj = 0; jj < 4; ++jj) v[jj] = f2bf(acc[i][jq][jj]);
        *(ush4*)&vtbuf[((size_t)bb * 1024 + (e - 2048)) * N + t] = v;
      }
    }
  }
}

// ---------- GEMM out-proj: 64x128 tile -> 512 blocks = 2 blocks/CU ----------
__global__ __launch_bounds__(256) void gemm_out(const unsigned short* __restrict__ A,
                                                const unsigned short* __restrict__ Bt,
                                                float* __restrict__ outf) {
  __shared__ unsigned short Asm[64 * 64];
  __shared__ unsigned short Bsm[128 * 64];
  const int tid = threadIdx.x;
  const int lane = tid & 63, wid = tid >> 6;
  const int ln = lane & 15, lh = lane >> 4;
  const int wr = wid >> 1, wc = wid & 1;
  const int bid = blockIdx.x;            // 512 = 64 m-chunks x 8 n-chunks
  const int xcd = bid & 7, j = bid >> 3;
  const int m0 = (xcd * 8 + (j & 7)) * 64;
  const int n0 = (j >> 3) * 128;

  f32x4 acc[2][4];
#pragma unroll
  for (int i = 0; i < 2; ++i)
#pragma unroll
    for (int jq = 0; jq < 4; ++jq) acc[i][jq] = (f32x4){0.f, 0.f, 0.f, 0.f};

  for (int k0 = 0; k0 < 1024; k0 += 64) {
#pragma unroll
    for (int jj = 0; jj < 2; ++jj) {
      int slot = tid + jj * 256;
      int row = slot >> 3, u = slot & 7;
      int usw = (u ^ (row & 7)) * 8;
      gload16(&A[(size_t)(m0 + row) * 1024 + k0 + usw], &Asm[slot * 8]);
    }
#pragma unroll
    for (int jj = 0; jj < 4; ++jj) {
      int slot = tid + jj * 256;
      int row = slot >> 3, u = slot & 7;
      int usw = (u ^ (row & 7)) * 8;
      gload16(&Bt[(size_t)(n0 + row) * 1024 + k0 + usw], &Bsm[slot * 8]);
    }
    __syncthreads();
#pragma unroll
    for (int s = 0; s < 2; ++s) {
      short8 af[2], bfr[4];
#pragma unroll
      for (int i = 0; i < 2; ++i) {
        int row = wr * 32 + i * 16 + ln;
        int u = ((s * 4 + lh) ^ (row & 7)) * 8;
        af[i] = *(const short8*)&Asm[row * 64 + u];
      }
#pragma unroll
      for (int jq = 0; jq < 4; ++jq) {
        int row = wc * 64 + jq * 16 + ln;
        int u = ((s * 4 + lh) ^ (row & 7)) * 8;
        bfr[jq] = *(const short8*)&Bsm[row * 64 + u];
      }
#pragma unroll
      for (int i = 0; i < 2; ++i)
#pragma unroll
        for (int jq = 0; jq < 4; ++jq)
          acc[i][jq] = __builtin_amdgcn_mfma_f32_16x16x32_bf16(af[i], bfr[jq], acc[i][jq], 0, 0, 0);
    }
    __syncthreads();
  }

#pragma unroll
  for (int i = 0; i < 2; ++i) {
    int mrow = m0 + wr * 32 + i * 16 + lh * 4;
    int bb = mrow >> 11, t = mrow & 2047;
#pragma unroll
    for (int jq = 0; jq < 4; ++jq) {
      int e = n0 + wc * 64 + jq * 16 + ln;
      float* op = outf + (size_t)bb * D * N + (size_t)e * N + t;
      *(f32x4*)op = acc[i][jq];
    }
  }
}

// ---------- RoPE: K section only (Q-rope folded into attn's Q load) ----------
__global__ void rope_kernel(unsigned short* __restrict__ qk, const float2* __restrict__ tab) {
  int idx = blockIdx.x * 256 + threadIdx.x;  // B*N*1024/8 = 524,288
  int e = 1024 + (idx & 127) * 8;
  int t = (idx >> 7) & 2047;
  int bb = idx >> 18;
  int p0 = (e & 63) >> 1;
  unsigned short* p = qk + ((size_t)(bb * N + t)) * 2048 + e;
  short8 v = *(short8*)p;
#pragma unroll
  for (int q = 0; q < 4; ++q) {
    float2 cs = tab[t * 32 + p0 + q];
    float xe = bf2f((unsigned short)v[2 * q]);
    float xo = bf2f((unsigned short)v[2 * q + 1]);
    v[2 * q] = (short)f2bf(xe * cs.x - xo * cs.y);
    v[2 * q + 1] = (short)f2bf(xe * cs.y + xo * cs.x);
  }
  *(short8*)p = v;
}

// ---------- flash attention: T15 software pipeline QK(t) || FINISH(t-1) ----------
// (R19 verbatim — best measured attn: ~56.8 us.)
__global__ __launch_bounds__(256, 2) void attn_kernel(const unsigned short* __restrict__ qk,
                                                      const unsigned short* __restrict__ vt,
                                                      unsigned short* __restrict__ ob,
                                                      const float2* __restrict__ tab) {
  __shared__ unsigned short Ksm[3][64 * 64];  // [key][d]
  __shared__ unsigned short Vsm[3][64 * 64];  // [d][key]
  const int tid = threadIdx.x;
  const int lane = tid & 63, wid = tid >> 6;
  const int l31 = lane & 31, hi = lane >> 5;
  const int L = blockIdx.x;
  const int hh = L & 31, qb = L >> 5;
  const int bb = hh >> 4, h = hh & 15;
  const unsigned short* Qg = qk + (size_t)bb * N * 2048 + h * 64;
  const unsigned short* Kg = Qg + 1024;
  const unsigned short* Vg = vt + ((size_t)bb * 1024 + h * 64) * N;

  const int q = qb * 128 + wid * 32 + l31;
  const float qscl = 0.125f * 1.4426950408889634f;  // hd^-0.5 * log2(e)
  short8 qf[4];
#pragma unroll
  for (int c = 0; c < 4; ++c) {
    short8 raw = *(const short8*)&Qg[(size_t)q * 2048 + c * 16 + hi * 8];
    short8 f;
#pragma unroll
    for (int pp = 0; pp < 4; ++pp) {
      float2 cs = tab[q * 32 + c * 8 + hi * 4 + pp];
      float xe = bf2f((unsigned short)raw[2 * pp]);
      float xo = bf2f((unsigned short)raw[2 * pp + 1]);
      f[2 * pp] = (short)f2bf((xe * cs.x - xo * cs.y) * qscl);
      f[2 * pp + 1] = (short)f2bf((xe * cs.y + xo * cs.x) * qscl);
    }
    qf[c] = f;
  }

  short8 ones_f;
#pragma unroll
  for (int j = 0; j < 8; ++j) ones_f[j] = (short)0x3F80;

  f32x16 z16;
#pragma unroll
  for (int r = 0; r < 16; ++r) z16[r] = 0.f;
  f32x16 oL = z16, oH = z16, lacc = z16;

  auto STAGE = [&](int buf, int kb) {
#pragma unroll
    for (int jj = 0; jj < 2; ++jj) {
      int slot = tid + jj * 256;
      int row = slot >> 3, u = slot & 7;
      int usw = (u ^ (row & 7)) * 8;
      gload16(&Kg[(size_t)(kb + row) * 2048 + usw], &Ksm[buf][slot * 8]);
    }
#pragma unroll
    for (int jj = 0; jj < 2; ++jj) {
      int slot = tid + jj * 256;
      int row = slot >> 3, u = slot & 7;
      int usw = (u ^ (row & 7)) * 8;
      gload16(&Vg[(size_t)row * N + kb + usw], &Vsm[buf][slot * 8]);
    }
  };

  auto QK = [&](int buf, f32x16& s0, f32x16& s1) {
    const unsigned short* Kb = Ksm[buf];
    {
      short8 ka = *(const short8*)&Kb[l31 * 64 + (((0 + hi) ^ (l31 & 7)) * 8)];
      s0 = __builtin_amdgcn_mfma_f32_32x32x16_bf16(ka, qf[0], z16, 0, 0, 0);
      int r1 = 32 + l31;
      short8 kc = *(const short8*)&Kb[r1 * 64 + (((0 + hi) ^ (r1 & 7)) * 8)];
      s1 = __builtin_amdgcn_mfma_f32_32x32x16_bf16(kc, qf[0], z16, 0, 0, 0);
    }
#pragma unroll
    for (int c = 1; c < 4; ++c) {
      short8 ka = *(const short8*)&Kb[l31 * 64 + (((c * 2 + hi) ^ (l31 & 7)) * 8)];
      s0 = __builtin_amdgcn_mfma_f32_32x32x16_bf16(ka, qf[c], s0, 0, 0, 0);
      int r1 = 32 + l31;
      short8 kc = *(const short8*)&Kb[r1 * 64 + (((c * 2 + hi) ^ (r1 & 7)) * 8)];
      s1 = __builtin_amdgcn_mfma_f32_32x32x16_bf16(kc, qf[c], s1, 0, 0, 0);
    }
  };

  auto FINISH = [&](f32x16& s0, f32x16& s1, int buf) {
    const unsigned short* Vb = Vsm[buf];
#pragma unroll
    for (int r = 0; r < 16; ++r) {
      s0[r] = __builtin_amdgcn_exp2f(s0[r]);
      s1[r] = __builtin_amdgcn_exp2f(s1[r]);
    }
    unsigned int W[16];
#pragma unroll
    for (int i = 0; i < 8; ++i) {
      W[i] = pk2(s0[2 * i], s0[2 * i + 1]);
      W[8 + i] = pk2(s1[2 * i], s1[2 * i + 1]);
    }
    short8 pf[4];
#pragma unroll
    for (int c = 0; c < 4; ++c) {
      unsigned int a0 = W[4 * c + 0], b0 = W[4 * c + 2];
      unsigned int a1 = W[4 * c + 1], b1 = W[4 * c + 3];
      asm volatile("v_permlane32_swap_b32 %0, %1" : "+v"(a0), "+v"(b0));
      asm volatile("v_permlane32_swap_b32 %0, %1" : "+v"(a1), "+v"(b1));
      pf[c] = mk_frag(a0, a1, b0, b1);
    }
#pragma unroll
    for (int c = 0; c < 4; ++c) {
      short8 va = *(const short8*)&Vb[l31 * 64 + (((c * 2 + hi) ^ (l31 & 7)) * 8)];
      oL = __builtin_amdgcn_mfma_f32_32x32x16_bf16(va, pf[c], oL, 0, 0, 0);
      int rH = 32 + l31;
      short8 vb = *(const short8*)&Vb[rH * 64 + (((c * 2 + hi) ^ (rH & 7)) * 8)];
      oH = __builtin_amdgcn_mfma_f32_32x32x16_bf16(vb, pf[c], oH, 0, 0, 0);
      lacc = __builtin_amdgcn_mfma_f32_32x32x16_bf16(ones_f, pf[c], lacc, 0, 0, 0);
    }
  };

  f32x16 sA0, sA1, sB0, sB1;
  // prologue: tile 0 staged+computed; tile 1 staged
  STAGE(0, 0);
  __syncthreads();
  QK(0, sA0, sA1);
  STAGE(1, 64);
  __syncthreads();
  // main: pairs (t, t+1) for t = 1,3,...,29  (tiles 1..30)
  for (int t = 1; t < 31; t += 2) {
    int bq = t % 3, bn = (t + 1) % 3, bp = (t - 1) % 3;
    // odd step t: QK(t) -> sB; stage t+1; finish tile t-1 (sA)
    QK(bq, sB0, sB1);
    STAGE(bn, (t + 1) * 64);
    FINISH(sA0, sA1, bp);
    __syncthreads();
    // even step t+1: QK(t+1) -> sA; stage t+2; finish tile t (sB)
    QK(bn, sA0, sA1);
    STAGE(bp, (t + 2) * 64);   // (t+2)%3 == (t-1)%3
    FINISH(sB0, sB1, bq);
    __syncthreads();
  }
  // epilogue: tile 31 (staged during the last even step, barrier passed)
  QK(31 % 3, sB0, sB1);
  FINISH(sA0, sA1, 30 % 3);
  FINISH(sB0, sB1, 31 % 3);

  float inv = 1.f / lacc[0];  // every row of lacc = full l for this lane's q
  unsigned short* obp = ob + ((size_t)(bb * N + q)) * 1024 + h * 64;
#pragma unroll
  for (int r4 = 0; r4 < 4; ++r4) {
    ush4 vL, vH;
#pragma unroll
    for (int i = 0; i < 4; ++i) {
      vL[i] = f2bf(oL[r4 * 4 + i] * inv);
      vH[i] = f2bf(oH[r4 * 4 + i] * inv);
    }
    *(ush4*)&obp[r4 * 8 + hi * 4] = vL;
    *(ush4*)&obp[32 + r4 * 8 + hi * 4] = vH;
  }
}

extern "C" void kernel_launch(void* const* d_in, const int* in_sizes, int n_in,
                              void* d_out, int out_size, void* d_ws, size_t ws_size,
                              hipStream_t stream) {
  const float* x = (const float*)d_in[0];
  const float* w_qkv = (const float*)d_in[1];
  const float* w_out = (const float*)d_in[2];
  float* out = (float*)d_out;
  char* ws = (char*)d_ws;

  unsigned short* wqkv_bf = (unsigned short*)ws;                    // 6 MB
  unsigned short* wout_bf = (unsigned short*)(ws + 6291456);        // 2 MB
  unsigned short* xt      = (unsigned short*)(ws + 8388608);        // 8 MB (reused as obuf)
  unsigned short* qkbuf   = (unsigned short*)(ws + 16777216);       // 16 MB
  unsigned short* vtbuf   = (unsigned short*)(ws + 33554432);       // 8 MB
  float2* tab             = (float2*)(ws + 41943040);               // 0.5 MB

  prep_k<<<8448, 256, 0, stream>>>(w_qkv, wqkv_bf, w_out, wout_bf, tab, x, xt);

  gemm_qkv<<<768, 512, 0, stream>>>(xt, wqkv_bf, qkbuf, vtbuf);
  rope_kernel<<<2048, 256, 0, stream>>>(qkbuf, tab);
  attn_kernel<<<512, 256, 0, stream>>>(qkbuf, vtbuf, xt /* obuf */, tab);
  gemm_out<<<512, 256, 0, stream>>>(xt, wout_bf, out);
}

// Round 21
// 116.614 us; speedup vs baseline: 1.0130x; 1.0130x over previous
//
#include <hip/hip_runtime.h>
#include <hip/hip_bf16.h>
#include <math.h>

#define B 2
#define N 2048
#define D 1024
#define H 16
#define HD 64

typedef __attribute__((ext_vector_type(8))) short short8;
typedef __attribute__((ext_vector_type(4))) float f32x4;
typedef __attribute__((ext_vector_type(16))) float f32x16;
typedef __attribute__((ext_vector_type(4))) unsigned short ush4;
typedef __attribute__((ext_vector_type(4))) unsigned int uint4v;

__device__ __forceinline__ float bf2f(unsigned short u) {
  unsigned int x = ((unsigned int)u) << 16;
  float f;
  __builtin_memcpy(&f, &x, 4);
  return f;
}
__device__ __forceinline__ unsigned short f2bf(float f) {
  unsigned int x;
  __builtin_memcpy(&x, &f, 4);
  x = x + 0x7fffu + ((x >> 16) & 1u);
  return (unsigned short)(x >> 16);
}
__device__ __forceinline__ unsigned int pk2(float lo, float hi) {
  union { __hip_bfloat162 h; unsigned int u; } cv;
  cv.h = __float22bfloat162_rn(make_float2(lo, hi));
  return cv.u;
}
__device__ __forceinline__ short8 mk_frag(unsigned int w0, unsigned int w1,
                                          unsigned int w2, unsigned int w3) {
  union { uint4v u; short8 s; } cv;
  cv.u = (uint4v){w0, w1, w2, w3};
  return cv.s;
}

// async global->LDS, 16B per lane. LDS dest linear (base + lane*16);
// swizzle lives in the per-lane GLOBAL address (m173/m201 pattern).
__device__ __forceinline__ void gload16(const unsigned short* g, unsigned short* l) {
  __builtin_amdgcn_global_load_lds(
      (const __attribute__((address_space(1))) unsigned int*)(const void*)g,
      (__attribute__((address_space(3))) unsigned int*)(void*)l, 16, 0, 0);
}

// ---------- prep: weight conversions + rope table + x-transpose, ONE launch ----------
__global__ __launch_bounds__(256) void prep_k(const float* __restrict__ wqkv,
                                              unsigned short* __restrict__ wqkv_bf,
                                              const float* __restrict__ wout,
                                              unsigned short* __restrict__ wout_bf,
                                              float2* __restrict__ tab,
                                              const float* __restrict__ x,
                                              unsigned short* __restrict__ xt) {
  int blk = blockIdx.x;
  int tid = threadIdx.x;
  if (blk < 4096) {
    const float* src = (blk < 3072) ? wqkv : wout;
    unsigned short* dst = (blk < 3072) ? wqkv_bf : wout_bf;
    int i = (blk < 3072 ? blk : blk - 3072) * 256 + tid;
    float4 v = ((const float4*)src)[i];
    ush4 o;
    o[0] = f2bf(v.x); o[1] = f2bf(v.y); o[2] = f2bf(v.z); o[3] = f2bf(v.w);
    *(ush4*)&dst[i * 4] = o;
  } else if (blk < 4352) {
    int idx = (blk - 4096) * 256 + tid;  // 2048*32
    int t = idx >> 5, p = idx & 31;
    float inv = powf(10000.f, -(float)p / 32.f);
    float ang = (float)t * inv;
    float s, c;
    sincosf(ang, &s, &c);
    tab[idx] = make_float2(c, s);
  } else {
    __shared__ float tile[32][33];
    int tb = blk - 4352;                 // grid (64, 32, 2) flattened
    int t0 = (tb & 63) * 32, d0 = ((tb >> 6) & 31) * 32, bb = tb >> 11;
    int tx = tid & 31, ty = tid >> 5;
#pragma unroll
    for (int i = 0; i < 4; ++i) {
      int r = ty * 4 + i;
      tile[r][tx] = x[(size_t)bb * D * N + (size_t)(d0 + r) * N + t0 + tx];
    }
    __syncthreads();
#pragma unroll
    for (int i = 0; i < 4; ++i) {
      int r = ty * 4 + i;
      xt[((size_t)(bb * N) + t0 + r) * D + d0 + tx] = f2bf(tile[tx][r]);
    }
  }
}

// ---------- GEMM qkv: 128x128 tile, BK=64, 4 waves, XCD swizzle ----------
__global__ __launch_bounds__(256) void gemm_qkv(const unsigned short* __restrict__ A,
                                                const unsigned short* __restrict__ Bt,
                                                unsigned short* __restrict__ qkbuf,
                                                unsigned short* __restrict__ vtbuf) {
  __shared__ unsigned short Asm[128 * 64];
  __shared__ unsigned short Bsm[128 * 64];
  const int tid = threadIdx.x;
  const int lane = tid & 63, wid = tid >> 6;
  const int ln = lane & 15, lh = lane >> 4;
  const int wr = wid >> 1, wc = wid & 1;
  const int bid = blockIdx.x;
  const int xcd = bid & 7, j = bid >> 3;
  const int m0 = (xcd * 4 + (j & 3)) * 128;
  const int n0 = (j >> 2) * 128;

  f32x4 acc[4][4];
#pragma unroll
  for (int i = 0; i < 4; ++i)
#pragma unroll
    for (int jq = 0; jq < 4; ++jq) acc[i][jq] = (f32x4){0.f, 0.f, 0.f, 0.f};

  for (int k0 = 0; k0 < 1024; k0 += 64) {
#pragma unroll
    for (int jj = 0; jj < 4; ++jj) {
      int slot = tid + jj * 256;
      int row = slot >> 3, u = slot & 7;
      int usw = (u ^ (row & 7)) * 8;
      gload16(&A[(size_t)(m0 + row) * 1024 + k0 + usw], &Asm[slot * 8]);
    }
#pragma unroll
    for (int jj = 0; jj < 4; ++jj) {
      int slot = tid + jj * 256;
      int row = slot >> 3, u = slot & 7;
      int usw = (u ^ (row & 7)) * 8;
      gload16(&Bt[(size_t)(n0 + row) * 1024 + k0 + usw], &Bsm[slot * 8]);
    }
    __syncthreads();
#pragma unroll
    for (int s = 0; s < 2; ++s) {
      short8 af[4], bfr[4];
#pragma unroll
      for (int i = 0; i < 4; ++i) {
        int row = wr * 64 + i * 16 + ln;
        int u = ((s * 4 + lh) ^ (row & 7)) * 8;
        af[i] = *(const short8*)&Asm[row * 64 + u];
      }
#pragma unroll
      for (int jq = 0; jq < 4; ++jq) {
        int row = wc * 64 + jq * 16 + ln;
        int u = ((s * 4 + lh) ^ (row & 7)) * 8;
        bfr[jq] = *(const short8*)&Bsm[row * 64 + u];
      }
#pragma unroll
      for (int i = 0; i < 4; ++i)
#pragma unroll
        for (int jq = 0; jq < 4; ++jq)
          acc[i][jq] = __builtin_amdgcn_mfma_f32_16x16x32_bf16(af[i], bfr[jq], acc[i][jq], 0, 0, 0);
    }
    __syncthreads();
  }

#pragma unroll
  for (int i = 0; i < 4; ++i) {
    int mrow = m0 + wr * 64 + i * 16 + lh * 4;
    int bb = mrow >> 11, t = mrow & 2047;
#pragma unroll
    for (int jq = 0; jq < 4; ++jq) {
      int e = n0 + wc * 64 + jq * 16 + ln;
      if (e < 2048) {
#pragma unroll
        for (int jj = 0; jj < 4; ++jj)
          qkbuf[((size_t)(bb * N + t + jj)) * 2048 + e] = f2bf(acc[i][jq][jj]);
      } else {
        ush4 v;
#pragma unroll
        for (int jj = 0; jj < 4; ++jj) v[jj] = f2bf(acc[i][jq][jj]);
        *(ush4*)&vtbuf[((size_t)bb * 1024 + (e - 2048)) * N + t] = v;
      }
    }
  }
}

// ---------- GEMM out-proj: 64x128 tile -> 512 blocks = 2 blocks/CU ----------
__global__ __launch_bounds__(256) void gemm_out(const unsigned short* __restrict__ A,
                                                const unsigned short* __restrict__ Bt,
                                                float* __restrict__ outf) {
  __shared__ unsigned short Asm[64 * 64];
  __shared__ unsigned short Bsm[128 * 64];
  const int tid = threadIdx.x;
  const int lane = tid & 63, wid = tid >> 6;
  const int ln = lane & 15, lh = lane >> 4;
  const int wr = wid >> 1, wc = wid & 1;
  const int bid = blockIdx.x;            // 512 = 64 m-chunks x 8 n-chunks
  const int xcd = bid & 7, j = bid >> 3;
  const int m0 = (xcd * 8 + (j & 7)) * 64;
  const int n0 = (j >> 3) * 128;

  f32x4 acc[2][4];
#pragma unroll
  for (int i = 0; i < 2; ++i)
#pragma unroll
    for (int jq = 0; jq < 4; ++jq) acc[i][jq] = (f32x4){0.f, 0.f, 0.f, 0.f};

  for (int k0 = 0; k0 < 1024; k0 += 64) {
#pragma unroll
    for (int jj = 0; jj < 2; ++jj) {
      int slot = tid + jj * 256;
      int row = slot >> 3, u = slot & 7;
      int usw = (u ^ (row & 7)) * 8;
      gload16(&A[(size_t)(m0 + row) * 1024 + k0 + usw], &Asm[slot * 8]);
    }
#pragma unroll
    for (int jj = 0; jj < 4; ++jj) {
      int slot = tid + jj * 256;
      int row = slot >> 3, u = slot & 7;
      int usw = (u ^ (row & 7)) * 8;
      gload16(&Bt[(size_t)(n0 + row) * 1024 + k0 + usw], &Bsm[slot * 8]);
    }
    __syncthreads();
#pragma unroll
    for (int s = 0; s < 2; ++s) {
      short8 af[2], bfr[4];
#pragma unroll
      for (int i = 0; i < 2; ++i) {
        int row = wr * 32 + i * 16 + ln;
        int u = ((s * 4 + lh) ^ (row & 7)) * 8;
        af[i] = *(const short8*)&Asm[row * 64 + u];
      }
#pragma unroll
      for (int jq = 0; jq < 4; ++jq) {
        int row = wc * 64 + jq * 16 + ln;
        int u = ((s * 4 + lh) ^ (row & 7)) * 8;
        bfr[jq] = *(const short8*)&Bsm[row * 64 + u];
      }
#pragma unroll
      for (int i = 0; i < 2; ++i)
#pragma unroll
        for (int jq = 0; jq < 4; ++jq)
          acc[i][jq] = __builtin_amdgcn_mfma_f32_16x16x32_bf16(af[i], bfr[jq], acc[i][jq], 0, 0, 0);
    }
    __syncthreads();
  }

#pragma unroll
  for (int i = 0; i < 2; ++i) {
    int mrow = m0 + wr * 32 + i * 16 + lh * 4;
    int bb = mrow >> 11, t = mrow & 2047;
#pragma unroll
    for (int jq = 0; jq < 4; ++jq) {
      int e = n0 + wc * 64 + jq * 16 + ln;
      float* op = outf + (size_t)bb * D * N + (size_t)e * N + t;
      *(f32x4*)op = acc[i][jq];
    }
  }
}

// ---------- RoPE: K section only (Q-rope folded into attn's Q load) ----------
__global__ void rope_kernel(unsigned short* __restrict__ qk, const float2* __restrict__ tab) {
  int idx = blockIdx.x * 256 + threadIdx.x;  // B*N*1024/8 = 524,288
  int e = 1024 + (idx & 127) * 8;
  int t = (idx >> 7) & 2047;
  int bb = idx >> 18;
  int p0 = (e & 63) >> 1;
  unsigned short* p = qk + ((size_t)(bb * N + t)) * 2048 + e;
  short8 v = *(short8*)p;
#pragma unroll
  for (int q = 0; q < 4; ++q) {
    float2 cs = tab[t * 32 + p0 + q];
    float xe = bf2f((unsigned short)v[2 * q]);
    float xo = bf2f((unsigned short)v[2 * q + 1]);
    v[2 * q] = (short)f2bf(xe * cs.x - xo * cs.y);
    v[2 * q + 1] = (short)f2bf(xe * cs.y + xo * cs.x);
  }
  *(short8*)p = v;
}

// ---------- flash attention: T15 software pipeline QK(t) || FINISH(t-1) ----------
// (R19 verbatim — best measured attn: ~56.8 us.)
__global__ __launch_bounds__(256, 2) void attn_kernel(const unsigned short* __restrict__ qk,
                                                      const unsigned short* __restrict__ vt,
                                                      unsigned short* __restrict__ ob,
                                                      const float2* __restrict__ tab) {
  __shared__ unsigned short Ksm[3][64 * 64];  // [key][d]
  __shared__ unsigned short Vsm[3][64 * 64];  // [d][key]
  const int tid = threadIdx.x;
  const int lane = tid & 63, wid = tid >> 6;
  const int l31 = lane & 31, hi = lane >> 5;
  const int L = blockIdx.x;
  const int hh = L & 31, qb = L >> 5;
  const int bb = hh >> 4, h = hh & 15;
  const unsigned short* Qg = qk + (size_t)bb * N * 2048 + h * 64;
  const unsigned short* Kg = Qg + 1024;
  const unsigned short* Vg = vt + ((size_t)bb * 1024 + h * 64) * N;

  const int q = qb * 128 + wid * 32 + l31;
  const float qscl = 0.125f * 1.4426950408889634f;  // hd^-0.5 * log2(e)
  short8 qf[4];
#pragma unroll
  for (int c = 0; c < 4; ++c) {
    short8 raw = *(const short8*)&Qg[(size_t)q * 2048 + c * 16 + hi * 8];
    short8 f;
#pragma unroll
    for (int pp = 0; pp < 4; ++pp) {
      float2 cs = tab[q * 32 + c * 8 + hi * 4 + pp];
      float xe = bf2f((unsigned short)raw[2 * pp]);
      float xo = bf2f((unsigned short)raw[2 * pp + 1]);
      f[2 * pp] = (short)f2bf((xe * cs.x - xo * cs.y) * qscl);
      f[2 * pp + 1] = (short)f2bf((xe * cs.y + xo * cs.x) * qscl);
    }
    qf[c] = f;
  }

  short8 ones_f;
#pragma unroll
  for (int j = 0; j < 8; ++j) ones_f[j] = (short)0x3F80;

  f32x16 z16;
#pragma unroll
  for (int r = 0; r < 16; ++r) z16[r] = 0.f;
  f32x16 oL = z16, oH = z16, lacc = z16;

  auto STAGE = [&](int buf, int kb) {
#pragma unroll
    for (int jj = 0; jj < 2; ++jj) {
      int slot = tid + jj * 256;
      int row = slot >> 3, u = slot & 7;
      int usw = (u ^ (row & 7)) * 8;
      gload16(&Kg[(size_t)(kb + row) * 2048 + usw], &Ksm[buf][slot * 8]);
    }
#pragma unroll
    for (int jj = 0; jj < 2; ++jj) {
      int slot = tid + jj * 256;
      int row = slot >> 3, u = slot & 7;
      int usw = (u ^ (row & 7)) * 8;
      gload16(&Vg[(size_t)row * N + kb + usw], &Vsm[buf][slot * 8]);
    }
  };

  auto QK = [&](int buf, f32x16& s0, f32x16& s1) {
    const unsigned short* Kb = Ksm[buf];
    {
      short8 ka = *(const short8*)&Kb[l31 * 64 + (((0 + hi) ^ (l31 & 7)) * 8)];
      s0 = __builtin_amdgcn_mfma_f32_32x32x16_bf16(ka, qf[0], z16, 0, 0, 0);
      int r1 = 32 + l31;
      short8 kc = *(const short8*)&Kb[r1 * 64 + (((0 + hi) ^ (r1 & 7)) * 8)];
      s1 = __builtin_amdgcn_mfma_f32_32x32x16_bf16(kc, qf[0], z16, 0, 0, 0);
    }
#pragma unroll
    for (int c = 1; c < 4; ++c) {
      short8 ka = *(const short8*)&Kb[l31 * 64 + (((c * 2 + hi) ^ (l31 & 7)) * 8)];
      s0 = __builtin_amdgcn_mfma_f32_32x32x16_bf16(ka, qf[c], s0, 0, 0, 0);
      int r1 = 32 + l31;
      short8 kc = *(const short8*)&Kb[r1 * 64 + (((c * 2 + hi) ^ (r1 & 7)) * 8)];
      s1 = __builtin_amdgcn_mfma_f32_32x32x16_bf16(kc, qf[c], s1, 0, 0, 0);
    }
  };

  auto FINISH = [&](f32x16& s0, f32x16& s1, int buf) {
    const unsigned short* Vb = Vsm[buf];
#pragma unroll
    for (int r = 0; r < 16; ++r) {
      s0[r] = __builtin_amdgcn_exp2f(s0[r]);
      s1[r] = __builtin_amdgcn_exp2f(s1[r]);
    }
    unsigned int W[16];
#pragma unroll
    for (int i = 0; i < 8; ++i) {
      W[i] = pk2(s0[2 * i], s0[2 * i + 1]);
      W[8 + i] = pk2(s1[2 * i], s1[2 * i + 1]);
    }
    short8 pf[4];
#pragma unroll
    for (int c = 0; c < 4; ++c) {
      unsigned int a0 = W[4 * c + 0], b0 = W[4 * c + 2];
      unsigned int a1 = W[4 * c + 1], b1 = W[4 * c + 3];
      asm volatile("v_permlane32_swap_b32 %0, %1" : "+v"(a0), "+v"(b0));
      asm volatile("v_permlane32_swap_b32 %0, %1" : "+v"(a1), "+v"(b1));
      pf[c] = mk_frag(a0, a1, b0, b1);
    }
#pragma unroll
    for (int c = 0; c < 4; ++c) {
      short8 va = *(const short8*)&Vb[l31 * 64 + (((c * 2 + hi) ^ (l31 & 7)) * 8)];
      oL = __builtin_amdgcn_mfma_f32_32x32x16_bf16(va, pf[c], oL, 0, 0, 0);
      int rH = 32 + l31;
      short8 vb = *(const short8*)&Vb[rH * 64 + (((c * 2 + hi) ^ (rH & 7)) * 8)];
      oH = __builtin_amdgcn_mfma_f32_32x32x16_bf16(vb, pf[c], oH, 0, 0, 0);
      lacc = __builtin_amdgcn_mfma_f32_32x32x16_bf16(ones_f, pf[c], lacc, 0, 0, 0);
    }
  };

  f32x16 sA0, sA1, sB0, sB1;
  // prologue: tile 0 staged+computed; tile 1 staged
  STAGE(0, 0);
  __syncthreads();
  QK(0, sA0, sA1);
  STAGE(1, 64);
  __syncthreads();
  // main: pairs (t, t+1) for t = 1,3,...,29  (tiles 1..30)
  for (int t = 1; t < 31; t += 2) {
    int bq = t % 3, bn = (t + 1) % 3, bp = (t - 1) % 3;
    // odd step t: QK(t) -> sB; stage t+1; finish tile t-1 (sA)
    QK(bq, sB0, sB1);
    STAGE(bn, (t + 1) * 64);
    FINISH(sA0, sA1, bp);
    __syncthreads();
    // even step t+1: QK(t+1) -> sA; stage t+2; finish tile t (sB)
    QK(bn, sA0, sA1);
    STAGE(bp, (t + 2) * 64);   // (t+2)%3 == (t-1)%3
    FINISH(sB0, sB1, bq);
    __syncthreads();
  }
  // epilogue: tile 31 (staged during the last even step, barrier passed)
  QK(31 % 3, sB0, sB1);
  FINISH(sA0, sA1, 30 % 3);
  FINISH(sB0, sB1, 31 % 3);

  float inv = 1.f / lacc[0];  // every row of lacc = full l for this lane's q
  unsigned short* obp = ob + ((size_t)(bb * N + q)) * 1024 + h * 64;
#pragma unroll
  for (int r4 = 0; r4 < 4; ++r4) {
    ush4 vL, vH;
#pragma unroll
    for (int i = 0; i < 4; ++i) {
      vL[i] = f2bf(oL[r4 * 4 + i] * inv);
      vH[i] = f2bf(oH[r4 * 4 + i] * inv);
    }
    *(ush4*)&obp[r4 * 8 + hi * 4] = vL;
    *(ush4*)&obp[32 + r4 * 8 + hi * 4] = vH;
  }
}

extern "C" void kernel_launch(void* const* d_in, const int* in_sizes, int n_in,
                              void* d_out, int out_size, void* d_ws, size_t ws_size,
                              hipStream_t stream) {
  const float* x = (const float*)d_in[0];
  const float* w_qkv = (const float*)d_in[1];
  const float* w_out = (const float*)d_in[2];
  float* out = (float*)d_out;
  char* ws = (char*)d_ws;

  unsigned short* wqkv_bf = (unsigned short*)ws;                    // 6 MB
  unsigned short* wout_bf = (unsigned short*)(ws + 6291456);        // 2 MB
  unsigned short* xt      = (unsigned short*)(ws + 8388608);        // 8 MB (reused as obuf)
  unsigned short* qkbuf   = (unsigned short*)(ws + 16777216);       // 16 MB
  unsigned short* vtbuf   = (unsigned short*)(ws + 33554432);       // 8 MB
  float2* tab             = (float2*)(ws + 41943040);               // 0.5 MB

  prep_k<<<8448, 256, 0, stream>>>(w_qkv, wqkv_bf, w_out, wout_bf, tab, x, xt);

  gemm_qkv<<<768, 256, 0, stream>>>(xt, wqkv_bf, qkbuf, vtbuf);
  rope_kernel<<<2048, 256, 0, stream>>>(qkbuf, tab);
  attn_kernel<<<512, 256, 0, stream>>>(qkbuf, vtbuf, xt /* obuf */, tab);
  gemm_out<<<512, 256, 0, stream>>>(xt, wout_bf, out);
}